// Round 7
// baseline (177.682 us; speedup 1.0000x reference)
//
#include <hip/hip_runtime.h>
#include <hip/hip_bf16.h>

#define IN_DIM 512
#define OUT_DIM 512

typedef unsigned short u16;
typedef __attribute__((ext_vector_type(4))) float f32x4;
typedef __attribute__((ext_vector_type(8))) __bf16 bf16x8;

// Direct global->LDS DMA, 16B per lane. LDS dest is wave-uniform base + lane*16.
#define GLD16(gp, lp) __builtin_amdgcn_global_load_lds(                       \
    (const __attribute__((address_space(1))) void*)(gp),                      \
    (__attribute__((address_space(3))) void*)(lp), 16, 0, 0)

#define VMCNT0() asm volatile("s_waitcnt vmcnt(0)" ::: "memory")
#define SB0()    __builtin_amdgcn_sched_barrier(0)

__device__ __forceinline__ float softplus_f(float r) {
    return (r > 15.0f) ? r : log1pf(expf(r));
}

// ---------------------------------------------------------------------------
// Kernel 1: fold w = w_mu + softplus(w_rho)*w_eps -> bf16 [OUT][IN] (K-major),
//           b = b_mu + softplus(b_rho)*b_eps -> f32 [OUT], into workspace.
// ---------------------------------------------------------------------------
__global__ void prep_kernel(const float* __restrict__ wmu, const float* __restrict__ wrho,
                            const float* __restrict__ weps, const float* __restrict__ bmu,
                            const float* __restrict__ brho, const float* __restrict__ beps,
                            u16* __restrict__ wbf, float* __restrict__ bias) {
    int gid = blockIdx.x * 256 + threadIdx.x;
    int i4 = gid * 4;
    const float4 mu  = *(const float4*)(wmu + i4);
    const float4 rho = *(const float4*)(wrho + i4);
    const float4 ep  = *(const float4*)(weps + i4);
    union { __bf16 h[4]; uint2 u; } pk;
    pk.h[0] = (__bf16)(mu.x + softplus_f(rho.x) * ep.x);
    pk.h[1] = (__bf16)(mu.y + softplus_f(rho.y) * ep.y);
    pk.h[2] = (__bf16)(mu.z + softplus_f(rho.z) * ep.z);
    pk.h[3] = (__bf16)(mu.w + softplus_f(rho.w) * ep.w);
    *(uint2*)(wbf + i4) = pk.u;
    if (gid < OUT_DIM) {
        bias[gid] = bmu[gid] + softplus_f(brho[gid]) * beps[gid];
    }
}

// ---------------------------------------------------------------------------
// Kernel 2: y = x @ w^T + b, fused dropout.  B-STATIONARY, barrier-free K-loop.
//
// Block 128M x 64N, 256 thr = 4 waves, wave = 32M x 64N (acc 2x4 f32x4).
// B half-panel (64 cols x 256 K bf16 = 32 KB) DMA'd to LDS once per phase
// (2 phases). K-loop has NO barriers: per step, waves independently
//   - build xf from depth-2 prefetched A regs (auto-wait = counted vmcnt(4))
//   - issue A(ks+2) global loads, SB0 fence
//   - 4 ds_read_b128 wf (source-swizzled, 2-way max) + 8 MFMA.
// Barriers only around the 2 panel stagings. 3 blocks/CU -> 12 decoupled waves.
// ---------------------------------------------------------------------------
__global__ __launch_bounds__(256, 3) void bayes_gemm_kernel(
    const float* __restrict__ x, const float* __restrict__ du,
    const u16* __restrict__ wbf, const float* __restrict__ bias,
    float* __restrict__ out)
{
    __shared__ u16 lB[64 * 256];   // 32 KB: [col][256 K] u16, chunk-swizzled

    const int raw   = blockIdx.x;
    const int lid   = (raw & 7) * 512 + (raw >> 3);   // 4096 % 8 == 0 -> bijective
    const int mband = lid >> 3;      // 0..511 : 128-row band
    const int nband = lid & 7;       // 0..7   : 64-col band

    const int tid  = threadIdx.x;
    const int lane = tid & 63;
    const int wv   = tid >> 6;
    const int l15  = lane & 15;
    const int lk   = lane >> 4;      // 0..3

    const int rowW = mband * 128 + wv * 32;   // wave's 32 output rows
    const int colb = nband * 64;

    // ---- A per-lane base pointers (direct global reads)
    const float* pa0 = x + (size_t)(rowW +      l15) * IN_DIM + lk * 8;  // m=0
    const float* pa1 = x + (size_t)(rowW + 16 + l15) * IN_DIM + lk * 8;  // m=1

    // ---- B staging geometry (rule 21: linear LDS dest, source pre-swizzled)
    // chunk = i*256 + tid; col c = i*8 + (tid>>5); pos p = tid&31;
    // stored(c,p) holds global chunk g = p ^ (c&7) = (tid&31) ^ (tid>>5).
    const int bc0 = tid >> 5;                       // 0..7
    const int bg  = (tid & 31) ^ bc0;
    const u16* gBsrc = wbf + (size_t)(colb + bc0) * IN_DIM + bg * 8;

    auto stageB = [&](int ph) {
#pragma unroll
        for (int i = 0; i < 8; ++i)
            GLD16(gBsrc + (size_t)i * 8 * IN_DIM + ph * 256,
                  &lB[i * 2048 + wv * 512]);
    };

    f32x4 acc[2][4] = {};   // [m][n]
    float4 aA0[4], aA1[4];  // depth-2 A prefetch buffers (static-indexed)

    auto loadA = [&](int t, float4* buf) {
        buf[0] = *(const float4*)(pa0 + t * 32);
        buf[1] = *(const float4*)(pa0 + t * 32 + 4);
        buf[2] = *(const float4*)(pa1 + t * 32);
        buf[3] = *(const float4*)(pa1 + t * 32 + 4);
    };

    // ---- prologue: A(0),A(1) in flight; panel phase 0 staged
    loadA(0, aA0);
    loadA(1, aA1);
    stageB(0);
    VMCNT0();
    __builtin_amdgcn_s_barrier();
    SB0();

#pragma unroll
    for (int ks = 0; ks < 16; ++ks) {
        const int s = ks & 7;            // step within phase
        float4* bufc = (ks & 1) ? aA1 : aA0;

        // build xf from A(ks) -- compiler emits counted vmcnt(4) here
        bf16x8 xf0, xf1;
        xf0[0] = (__bf16)bufc[0].x; xf0[1] = (__bf16)bufc[0].y;
        xf0[2] = (__bf16)bufc[0].z; xf0[3] = (__bf16)bufc[0].w;
        xf0[4] = (__bf16)bufc[1].x; xf0[5] = (__bf16)bufc[1].y;
        xf0[6] = (__bf16)bufc[1].z; xf0[7] = (__bf16)bufc[1].w;
        xf1[0] = (__bf16)bufc[2].x; xf1[1] = (__bf16)bufc[2].y;
        xf1[2] = (__bf16)bufc[2].z; xf1[3] = (__bf16)bufc[2].w;
        xf1[4] = (__bf16)bufc[3].x; xf1[5] = (__bf16)bufc[3].y;
        xf1[6] = (__bf16)bufc[3].z; xf1[7] = (__bf16)bufc[3].w;

        if (ks + 2 < 16) loadA(ks + 2, bufc);   // refill freed buffer, 2 ahead
        SB0();                                   // pin issue point

        // wf from LDS (swizzled read: p = (s*4+lk) ^ (col&7), 2-way max)
        bf16x8 wf[4];
#pragma unroll
        for (int n = 0; n < 4; ++n) {
            int c = n * 16 + l15;
            int p = (s * 4 + lk) ^ (c & 7);
            wf[n] = *(const bf16x8*)&lB[c * 256 + p * 8];
        }
#pragma unroll
        for (int n = 0; n < 4; ++n) {
            acc[0][n] = __builtin_amdgcn_mfma_f32_16x16x32_bf16(wf[n], xf0, acc[0][n], 0, 0, 0);
            acc[1][n] = __builtin_amdgcn_mfma_f32_16x16x32_bf16(wf[n], xf1, acc[1][n], 0, 0, 0);
        }

        // ---- phase swap after step 7 (only barriers in the kernel body)
        if (ks == 7) {
            __builtin_amdgcn_s_barrier();   // all waves done reading panel 0
            stageB(1);
            VMCNT0();                       // own DMAs done (A(8),A(9) drain too - once)
            __builtin_amdgcn_s_barrier();   // all waves' DMAs visible
            SB0();
        }
    }

    // ---- epilogue: bias + inverted dropout, dwordx4 throughout
#pragma unroll
    for (int m = 0; m < 2; ++m) {
#pragma unroll
        for (int n = 0; n < 4; ++n) {
            const int colB = colb + n * 16 + lk * 4;
            const float4 b4 = *(const float4*)(bias + colB);
            size_t off = (size_t)(rowW + m * 16 + l15) * OUT_DIM + colB;
            const float4 u4 = *(const float4*)(du + off);
            float4 o;
            o.x = (acc[m][n][0] + b4.x) * ((u4.x >= 0.2f) ? 1.25f : 0.0f);
            o.y = (acc[m][n][1] + b4.y) * ((u4.y >= 0.2f) ? 1.25f : 0.0f);
            o.z = (acc[m][n][2] + b4.z) * ((u4.z >= 0.2f) ? 1.25f : 0.0f);
            o.w = (acc[m][n][3] + b4.w) * ((u4.w >= 0.2f) ? 1.25f : 0.0f);
            *(float4*)(out + off) = o;
        }
    }
}

extern "C" void kernel_launch(void* const* d_in, const int* in_sizes, int n_in,
                              void* d_out, int out_size, void* d_ws, size_t ws_size,
                              hipStream_t stream) {
    const float* x    = (const float*)d_in[0];
    const float* wmu  = (const float*)d_in[1];
    const float* wrho = (const float*)d_in[2];
    const float* bmu  = (const float*)d_in[3];
    const float* brho = (const float*)d_in[4];
    const float* weps = (const float*)d_in[5];
    const float* beps = (const float*)d_in[6];
    const float* du   = (const float*)d_in[7];
    float* out = (float*)d_out;

    u16*   wbf  = (u16*)d_ws;
    float* bias = (float*)((char*)d_ws + OUT_DIM * IN_DIM * sizeof(u16));

    prep_kernel<<<256, 256, 0, stream>>>(wmu, wrho, weps, bmu, brho, beps, wbf, bias);
    // 512 M-bands x 8 N-bands
    bayes_gemm_kernel<<<4096, 256, 0, stream>>>(x, du, wbf, bias, out);
}

// Round 8
// 148.634 us; speedup vs baseline: 1.1954x; 1.1954x over previous
//
#include <hip/hip_runtime.h>
#include <hip/hip_bf16.h>

#define IN_DIM 512
#define OUT_DIM 512

typedef unsigned short u16;
typedef __attribute__((ext_vector_type(4))) float f32x4;
typedef __attribute__((ext_vector_type(8))) __bf16 bf16x8;

// Direct global->LDS DMA, 16B per lane. LDS dest is wave-uniform base + lane*16.
#define GLD16(gp, lp) __builtin_amdgcn_global_load_lds(                       \
    (const __attribute__((address_space(1))) void*)(gp),                      \
    (__attribute__((address_space(3))) void*)(lp), 16, 0, 0)

__device__ __forceinline__ float softplus_f(float r) {
    return (r > 15.0f) ? r : log1pf(expf(r));
}

// ---------------------------------------------------------------------------
// Kernel 1: fold w = w_mu + softplus(w_rho)*w_eps -> bf16 [OUT][IN] (K-major),
//           b = b_mu + softplus(b_rho)*b_eps -> f32 [OUT], into workspace.
// ---------------------------------------------------------------------------
__global__ void prep_kernel(const float* __restrict__ wmu, const float* __restrict__ wrho,
                            const float* __restrict__ weps, const float* __restrict__ bmu,
                            const float* __restrict__ brho, const float* __restrict__ beps,
                            u16* __restrict__ wbf, float* __restrict__ bias) {
    int gid = blockIdx.x * 256 + threadIdx.x;
    int i4 = gid * 4;
    const float4 mu  = *(const float4*)(wmu + i4);
    const float4 rho = *(const float4*)(wrho + i4);
    const float4 ep  = *(const float4*)(weps + i4);
    union { __bf16 h[4]; uint2 u; } pk;
    pk.h[0] = (__bf16)(mu.x + softplus_f(rho.x) * ep.x);
    pk.h[1] = (__bf16)(mu.y + softplus_f(rho.y) * ep.y);
    pk.h[2] = (__bf16)(mu.z + softplus_f(rho.z) * ep.z);
    pk.h[3] = (__bf16)(mu.w + softplus_f(rho.w) * ep.w);
    *(uint2*)(wbf + i4) = pk.u;
    if (gid < OUT_DIM) {
        bias[gid] = bmu[gid] + softplus_f(brho[gid]) * beps[gid];
    }
}

// ---------------------------------------------------------------------------
// Kernel 1b: x (f32) -> x_bf16, streaming. 4096 blocks x 256 thr, 8 float4/thr.
// Lane-consecutive float4 loads / uint2 stores (coalesced both sides).
// x_bf16 (67 MB) stays L3-resident for the GEMM -> no extra HBM round trip.
// ---------------------------------------------------------------------------
__global__ void cvt_kernel(const float* __restrict__ x, u16* __restrict__ xb) {
    const size_t base = (size_t)blockIdx.x * 8192 + threadIdx.x * 4;
#pragma unroll
    for (int i = 0; i < 8; ++i) {
        const float4 a = *(const float4*)(x + base + (size_t)i * 1024);
        union { __bf16 h[4]; uint2 u; } pk;
        pk.h[0] = (__bf16)a.x; pk.h[1] = (__bf16)a.y;
        pk.h[2] = (__bf16)a.z; pk.h[3] = (__bf16)a.w;
        *(uint2*)(xb + base + (size_t)i * 1024) = pk.u;
    }
}

// ---------------------------------------------------------------------------
// Kernel 2 (primary): y = x @ w^T + b, fused dropout. m97-faithful:
// 128x128 tile, BK=32, BOTH operands bf16 staged via global_load_lds into
// double-buffered LDS (8 KB each -> 32 KB total), plain 2-phase loop:
//   stage(t+1, buf^1); ds_read frags(buf); 16 MFMA; __syncthreads();
// Chunk swizzle (rule 21): stored(row,p) holds global chunk
//   g = p ^ (row&3) ^ ((row>>2)&3)   (16B chunks, 4 per 64B row)
// -> ds_read_b128 fragment reads are 2-way max (free). Source is
// pre-permuted per-lane; LDS dest stays linear for the DMA.
// ---------------------------------------------------------------------------
__global__ __launch_bounds__(256, 4) void bayes_gemm_kernel(
    const u16* __restrict__ xb, const float* __restrict__ du,
    const u16* __restrict__ wbf, const float* __restrict__ bias,
    float* __restrict__ out)
{
    __shared__ u16 lA[2][128 * 32];   // 8 KB per buffer
    __shared__ u16 lB[2][128 * 32];   // 8 KB per buffer

    const int raw   = blockIdx.x;
    const int lid   = (raw & 7) * 256 + (raw >> 3);   // 2048 % 8 == 0 -> bijective
    const int mband = lid >> 2;      // 0..511
    const int nband = lid & 3;       // 0..3

    const int tid  = threadIdx.x;
    const int lane = tid & 63;
    const int wv   = tid >> 6;
    const int wm   = wv >> 1;        // 0..1
    const int wn   = wv & 1;         // 0..1
    const int l15  = lane & 15;
    const int lk   = lane >> 4;      // 0..3

    const int row0 = mband * 128;
    const int colb = nband * 128;

    // ---- staging geometry: instr i of wave wv covers rows (i*4+wv)*16 + (lane>>2),
    // chunk p = lane&3 (LDS linear). Source chunk g = p ^ (row&3) ^ ((row>>2)&3)
    // = (lane&3) ^ ((lane>>2)&3) ^ ((lane>>4)&3)  (group-row bits vanish mod 4).
    const int sg   = ((lane & 3) ^ ((lane >> 2) & 3) ^ ((lane >> 4) & 3)) * 8;
    const int gr0  = (0 * 4 + wv) * 16 + (lane >> 2);
    const int gr1  = (1 * 4 + wv) * 16 + (lane >> 2);
    const u16* pA0 = xb  + (size_t)(row0 + gr0) * IN_DIM + sg;
    const u16* pA1 = xb  + (size_t)(row0 + gr1) * IN_DIM + sg;
    const u16* pB0 = wbf + (size_t)(colb + gr0) * IN_DIM + sg;
    const u16* pB1 = wbf + (size_t)(colb + gr1) * IN_DIM + sg;
    const int ldso0 = (0 * 4 + wv) * 512;   // elems
    const int ldso1 = (1 * 4 + wv) * 512;

    // fragment-read chunk permutation (same algebra as staging)
    const int ap = (lk ^ (l15 & 3) ^ ((l15 >> 2) & 3)) * 8;

    f32x4 acc[4][4] = {};   // [m][n]

    auto stage = [&](int t, int buf) {
        GLD16(pA0 + t * 32, &lA[buf][ldso0]);
        GLD16(pA1 + t * 32, &lA[buf][ldso1]);
        GLD16(pB0 + t * 32, &lB[buf][ldso0]);
        GLD16(pB1 + t * 32, &lB[buf][ldso1]);
    };

    // ---- prologue
    stage(0, 0);
    __syncthreads();

#pragma unroll
    for (int t = 0; t < 16; ++t) {
        const int buf = t & 1;
        if (t + 1 < 16) stage(t + 1, buf ^ 1);   // async DMA, in flight across compute

        bf16x8 bfr[4], afr[4];
#pragma unroll
        for (int n = 0; n < 4; ++n) {
            int r = wn * 64 + n * 16 + l15;
            bfr[n] = *(const bf16x8*)&lB[buf][r * 32 + ap];
        }
#pragma unroll
        for (int m = 0; m < 4; ++m) {
            int r = wm * 64 + m * 16 + l15;
            afr[m] = *(const bf16x8*)&lA[buf][r * 32 + ap];
        }
#pragma unroll
        for (int m = 0; m < 4; ++m)
#pragma unroll
            for (int n = 0; n < 4; ++n)
                acc[m][n] = __builtin_amdgcn_mfma_f32_16x16x32_bf16(
                    bfr[n], afr[m], acc[m][n], 0, 0, 0);

        __syncthreads();
    }

    // ---- epilogue: bias + inverted dropout, dwordx4 throughout
#pragma unroll
    for (int m = 0; m < 4; ++m) {
#pragma unroll
        for (int n = 0; n < 4; ++n) {
            const int colB = colb + wn * 64 + n * 16 + lk * 4;
            const float4 b4 = *(const float4*)(bias + colB);
            size_t off = (size_t)(row0 + wm * 64 + m * 16 + l15) * OUT_DIM + colB;
            const float4 u4 = *(const float4*)(du + off);
            float4 o;
            o.x = (acc[m][n][0] + b4.x) * ((u4.x >= 0.2f) ? 1.25f : 0.0f);
            o.y = (acc[m][n][1] + b4.y) * ((u4.y >= 0.2f) ? 1.25f : 0.0f);
            o.z = (acc[m][n][2] + b4.z) * ((u4.z >= 0.2f) ? 1.25f : 0.0f);
            o.w = (acc[m][n][3] + b4.w) * ((u4.w >= 0.2f) ? 1.25f : 0.0f);
            *(float4*)(out + off) = o;
        }
    }
}

// ---------------------------------------------------------------------------
// Fallback (ws too small for x_bf16): R5 kernel verbatim — f32-A staging.
// ---------------------------------------------------------------------------
__global__ __launch_bounds__(256, 3) void bayes_gemm_f32a(
    const float* __restrict__ x, const float* __restrict__ du,
    const u16* __restrict__ wbf, const float* __restrict__ bias,
    float* __restrict__ out)
{
    __shared__ float lAf[2][128 * 32];
    __shared__ u16   lBf[2][128 * 32];

    const int raw   = blockIdx.x;
    const int lid   = (raw & 7) * 256 + (raw >> 3);
    const int mband = lid >> 2;
    const int nband = lid & 3;

    const int tid  = threadIdx.x;
    const int lane = tid & 63;
    const int wv   = tid >> 6;
    const int wm   = wv >> 1;
    const int wn   = wv & 1;
    const int l15  = lane & 15;
    const int lk   = lane >> 4;

    const int row0 = mband * 128;
    const int colb = nband * 128;

    const int arow  = wv * 8 + (lane >> 3);
    const int acswz = ((lane & 7) ^ (lane >> 3)) * 4;
    const float* gA = x + (size_t)(row0 + arow) * IN_DIM + acswz;
    const int brow  = wv * 16 + (lane >> 2);
    const int bcswz = ((lane & 3) ^ ((lane >> 3) & 3)) * 8;
    const u16* gB = wbf + (size_t)(colb + brow) * IN_DIM + bcswz;

    f32x4 acc[4][4] = {};

    auto stage = [&](int t, int buf) {
#pragma unroll
        for (int i = 0; i < 4; ++i)
            GLD16(gA + (size_t)i * 32 * IN_DIM + t * 32, &lAf[buf][i * 1024 + wv * 256]);
#pragma unroll
        for (int i = 0; i < 2; ++i)
            GLD16(gB + (size_t)i * 64 * IN_DIM + t * 32, &lBf[buf][i * 2048 + wv * 512]);
    };

    stage(0, 0);
    __syncthreads();

#pragma unroll
    for (int t = 0; t < 16; ++t) {
        const int buf = t & 1;
        if (t + 1 < 16) stage(t + 1, buf ^ 1);

        bf16x8 wf[4];
#pragma unroll
        for (int n = 0; n < 4; ++n) {
            int r = wn * 64 + n * 16 + l15;
            int p = lk ^ ((l15 >> 1) & 3);
            wf[n] = *(const bf16x8*)&lBf[buf][r * 32 + p * 8];
        }
#pragma unroll
        for (int m = 0; m < 4; ++m) {
            int r  = wm * 64 + m * 16 + l15;
            int p0 = (2 * lk)     ^ (l15 & 7);
            int p1 = (2 * lk + 1) ^ (l15 & 7);
            float4 a0 = *(const float4*)&lAf[buf][r * 32 + p0 * 4];
            float4 a1 = *(const float4*)&lAf[buf][r * 32 + p1 * 4];
            bf16x8 xf;
            xf[0] = (__bf16)a0.x; xf[1] = (__bf16)a0.y;
            xf[2] = (__bf16)a0.z; xf[3] = (__bf16)a0.w;
            xf[4] = (__bf16)a1.x; xf[5] = (__bf16)a1.y;
            xf[6] = (__bf16)a1.z; xf[7] = (__bf16)a1.w;
#pragma unroll
            for (int n = 0; n < 4; ++n)
                acc[m][n] = __builtin_amdgcn_mfma_f32_16x16x32_bf16(
                    wf[n], xf, acc[m][n], 0, 0, 0);
        }
        __syncthreads();
    }

#pragma unroll
    for (int m = 0; m < 4; ++m) {
#pragma unroll
        for (int n = 0; n < 4; ++n) {
            const int colB = colb + wn * 64 + n * 16 + lk * 4;
            const float4 b4 = *(const float4*)(bias + colB);
            size_t off = (size_t)(row0 + wm * 64 + m * 16 + l15) * OUT_DIM + colB;
            const float4 u4 = *(const float4*)(du + off);
            float4 o;
            o.x = (acc[m][n][0] + b4.x) * ((u4.x >= 0.2f) ? 1.25f : 0.0f);
            o.y = (acc[m][n][1] + b4.y) * ((u4.y >= 0.2f) ? 1.25f : 0.0f);
            o.z = (acc[m][n][2] + b4.z) * ((u4.z >= 0.2f) ? 1.25f : 0.0f);
            o.w = (acc[m][n][3] + b4.w) * ((u4.w >= 0.2f) ? 1.25f : 0.0f);
            *(float4*)(out + off) = o;
        }
    }
}

extern "C" void kernel_launch(void* const* d_in, const int* in_sizes, int n_in,
                              void* d_out, int out_size, void* d_ws, size_t ws_size,
                              hipStream_t stream) {
    const float* x    = (const float*)d_in[0];
    const float* wmu  = (const float*)d_in[1];
    const float* wrho = (const float*)d_in[2];
    const float* bmu  = (const float*)d_in[3];
    const float* brho = (const float*)d_in[4];
    const float* weps = (const float*)d_in[5];
    const float* beps = (const float*)d_in[6];
    const float* du   = (const float*)d_in[7];
    float* out = (float*)d_out;

    u16*   wbf  = (u16*)d_ws;
    float* bias = (float*)((char*)d_ws + OUT_DIM * IN_DIM * sizeof(u16));
    u16*   xb   = (u16*)((char*)d_ws + (1 << 20));   // x_bf16 at +1 MB

    const size_t need = (1u << 20) + (size_t)65536 * IN_DIM * sizeof(u16);

    prep_kernel<<<256, 256, 0, stream>>>(wmu, wrho, weps, bmu, brho, beps, wbf, bias);

    if (ws_size >= need) {
        cvt_kernel<<<4096, 256, 0, stream>>>(x, xb);
        bayes_gemm_kernel<<<2048, 256, 0, stream>>>(xb, du, wbf, bias, out);
    } else {
        bayes_gemm_f32a<<<2048, 256, 0, stream>>>(x, du, wbf, bias, out);
    }
}